// Round 3
// baseline (103.056 us; speedup 1.0000x reference)
//
#include <hip/hip_runtime.h>
#include <stdint.h>

#define HH 512
#define WW 512
#define HWSZ (HH * WW)
#define NPB 8          // n-planes per block
#define RSTRIDE 520    // row: halo [3], data [4..515], halo [516]; 16B-aligned
#define NBUF 3

// async global->LDS, 16B per lane. LDS dest must be wave-uniform (HW adds lane*16B);
// global src is per-lane. AS casts via uintptr (CK's cast_pointer_to_* pattern).
__device__ __forceinline__ void gload16(const float* gsrc, float* ldst) {
    __builtin_amdgcn_global_load_lds(
        (const __attribute__((address_space(1))) void*)(uintptr_t)gsrc,
        (__attribute__((address_space(3))) void*)(uint32_t)(uintptr_t)ldst,
        16, 0, 0);
}

__global__ __launch_bounds__(128, 4) void fused_pipe(const float* __restrict__ img,
                                                     const float* __restrict__ x,
                                                     const float* __restrict__ kw,
                                                     const float* __restrict__ kb,
                                                     float* __restrict__ y) {
    __shared__ float rows[NBUF][3][RSTRIDE];
    __shared__ float trash[256];   // DMA target for out-of-bounds rows (content unused)

    const int tid  = threadIdx.x;          // 0..127 (2 waves)
    const int h    = blockIdx.x;           // 0..511
    const int n0   = blockIdx.y * NPB;
    const int w4   = tid * 4;
    const int wseg = (tid >> 6) * 256;     // wave-uniform half-row offset
    const bool vm1 = h > 0, vp1 = h < HH - 1;

    int  srcRow[3];
    bool valid[3];
    srcRow[0] = vm1 ? (h - 1) * WW : h * WW;  valid[0] = vm1;
    srcRow[1] = h * WW;                       valid[1] = true;
    srcRow[2] = vp1 ? (h + 1) * WW : h * WW;  valid[2] = vp1;

    // halo cells of every buffer: written once, never overwritten (DMA covers [4..515])
    if (tid < NBUF * 3) {
        rows[tid / 3][tid % 3][3]   = 0.0f;
        rows[tid / 3][tid % 3][516] = 0.0f;
    }
    // edge blocks: invalid row stays zero in ALL buffers; its DMA goes to trash
    if (!vm1 || !vp1) {
        const int bad = vm1 ? 2 : 0;
        for (int s = tid; s < NBUF * 128; s += 128) {
            int b = s >> 7, t = s & 127;
            *reinterpret_cast<float4*>(&rows[b][bad][4 + t * 4]) = make_float4(0, 0, 0, 0);
        }
    }

    // ---- stage image rows into buf0 (regular reg->LDS path, once) ----
    {
        float4 z = make_float4(0, 0, 0, 0);
        float4 r0 = vm1 ? *reinterpret_cast<const float4*>(img + (h - 1) * WW + w4) : z;
        float4 r1 =       *reinterpret_cast<const float4*>(img + h * WW + w4);
        float4 r2 = vp1 ? *reinterpret_cast<const float4*>(img + (h + 1) * WW + w4) : z;
        *reinterpret_cast<float4*>(&rows[0][0][4 + w4]) = r0;
        *reinterpret_cast<float4*>(&rows[0][1][4 + w4]) = r1;
        *reinterpret_cast<float4*>(&rows[0][2][4 + w4]) = r2;
    }
    __syncthreads();   // full sync ok here (nothing in flight yet)

    // read img neighborhood from LDS
    float iv[3][6];
#pragma unroll
    for (int i = 0; i < 3; ++i) {
        float4 v = *reinterpret_cast<const float4*>(&rows[0][i][4 + w4]);
        iv[i][0] = rows[0][i][3 + w4];
        iv[i][1] = v.x; iv[i][2] = v.y; iv[i][3] = v.z; iv[i][4] = v.w;
        iv[i][5] = rows[0][i][8 + w4];
    }

    // issue planes 0,1 (-> bufs 1,2); HBM latency hides under K-compute below
    auto issue_plane = [&](int p) {
        const float* xn = x + (size_t)(n0 + p) * HWSZ;
        const int b = (p + 1) % 3;
#pragma unroll
        for (int i = 0; i < 3; ++i) {
            const float* src = xn + srcRow[i] + tid * 4;           // per-lane, always in-bounds
            float* dst = valid[i] ? &rows[b][i][4 + wseg] : trash; // wave-uniform
            gload16(src, dst);
        }
    };
    issue_plane(0);
    issue_plane(1);

    // K[c][p] = kb[c] + sum_{i,q} img[h+i-1, w4+p+q-1] * kw[c,i,q]
    float Kr[9][4];
#pragma unroll
    for (int c = 0; c < 9; ++c) {
        float bv = kb[c];
#pragma unroll
        for (int p = 0; p < 4; ++p) Kr[c][p] = bv;
#pragma unroll
        for (int i = 0; i < 3; ++i)
#pragma unroll
            for (int q = 0; q < 3; ++q) {
                float wv = kw[c * 9 + i * 3 + q];
#pragma unroll
                for (int p = 0; p < 4; ++p)
                    Kr[c][p] = fmaf(iv[i][p + q], wv, Kr[c][p]);
            }
    }

    // raw barrier (NOT __syncthreads: keep planes 0,1 in flight). Protects buf0
    // (iv reads done in all waves) before plane 2's DMA targets it.
    asm volatile("" ::: "memory");
    __builtin_amdgcn_s_barrier();
    __builtin_amdgcn_sched_barrier(0);

    // ---- main pipeline: plane p lives in buf[(p+1)%3]; depth-2 prefetch ----
#pragma unroll
    for (int nn = 0; nn < NPB; ++nn) {
        if (nn + 2 < NPB) issue_plane(nn + 2);   // -> buf[nn%3]

        // wait until plane nn's 3 loads (this wave) have landed; counted, never 0.
        // queue: [p_nn x3][store_{nn-2}][p_{nn+1} x3][store_{nn-1}][p_{nn+2} x3]
        if (nn == 0)              asm volatile("s_waitcnt vmcnt(6)" ::: "memory");
        else if (nn < NPB - 2)    asm volatile("s_waitcnt vmcnt(7)" ::: "memory");
        else if (nn == NPB - 2)   asm volatile("s_waitcnt vmcnt(4)" ::: "memory");
        else                      asm volatile("s_waitcnt vmcnt(1)" ::: "memory");
        __builtin_amdgcn_s_barrier();            // B1: all waves' plane-nn data in LDS
        __builtin_amdgcn_sched_barrier(0);

        const int b = (nn + 1) % 3;
        float a[4] = {0, 0, 0, 0};
#pragma unroll
        for (int i = 0; i < 3; ++i) {
            float xv[6];
            float4 v = *reinterpret_cast<const float4*>(&rows[b][i][4 + w4]);
            xv[0] = rows[b][i][3 + w4];
            xv[1] = v.x; xv[2] = v.y; xv[3] = v.z; xv[4] = v.w;
            xv[5] = rows[b][i][8 + w4];
#pragma unroll
            for (int j = 0; j < 3; ++j) {
                const int c = i * 3 + j;
#pragma unroll
                for (int p = 0; p < 4; ++p)
                    a[p] = fmaf(xv[p + j], Kr[c][p], a[p]);
            }
        }
        *reinterpret_cast<float4*>(&y[(size_t)(n0 + nn) * HWSZ + h * WW + w4]) =
            make_float4(a[0], a[1], a[2], a[3]);

        __builtin_amdgcn_sched_barrier(0);
        __builtin_amdgcn_s_barrier();            // B2: confine waves to one iteration
        __builtin_amdgcn_sched_barrier(0);
    }
}

extern "C" void kernel_launch(void* const* d_in, const int* in_sizes, int n_in,
                              void* d_out, int out_size, void* d_ws, size_t ws_size,
                              hipStream_t stream) {
    const float* img = (const float*)d_in[0];   // (1, 512, 512)
    const float* x   = (const float*)d_in[1];   // (32, 1, 512, 512)
    const float* kw  = (const float*)d_in[2];   // (9, 1, 3, 3)
    const float* kb  = (const float*)d_in[3];   // (9,)
    float* y = (float*)d_out;                   // (32, 512, 512)

    dim3 grid(HH, 32 / NPB);   // 2048 blocks, 8/CU -> whole grid resident
    fused_pipe<<<grid, 128, 0, stream>>>(img, x, kw, kb, y);
}